// Round 2
// baseline (1161.703 us; speedup 1.0000x reference)
//
#include <hip/hip_runtime.h>
#include <hip/hip_bf16.h>

#define NB 8
#define DDIM 128
#define TDIM 128
#define HH 64
#define NHEAD 4
#define HDIM 16
#define NTHREADS 512

__device__ __forceinline__ float bf2f(__hip_bfloat16 x) { return __bfloat162float(x); }
__device__ __forceinline__ __hip_bfloat16 f2bf(float x) { return __float2bfloat16(x); }

__device__ __forceinline__ float wredsum(float v) {
#pragma unroll
    for (int off = 32; off; off >>= 1) v += __shfl_xor(v, off);
    return v;
}
__device__ __forceinline__ float wredmax(float v) {
#pragma unroll
    for (int off = 32; off; off >>= 1) v = fmaxf(v, __shfl_xor(v, off));
    return v;
}

__global__ __launch_bounds__(NTHREADS, 4) void gal_kernel(
    const float* __restrict__ h,  const float* __restrict__ W,
    const float* __restrict__ wq, const float* __restrict__ bq,
    const float* __restrict__ wk, const float* __restrict__ bk,
    const float* __restrict__ wv, const float* __restrict__ bv,
    const float* __restrict__ wo, const float* __restrict__ bo,
    const float* __restrict__ we, const float* __restrict__ be,
    const float* __restrict__ g1, const float* __restrict__ b1,
    const float* __restrict__ w1, const float* __restrict__ bf1,
    const float* __restrict__ w2, const float* __restrict__ bff2,
    const float* __restrict__ g2, const float* __restrict__ b2,
    float* __restrict__ out)
{
    // 64 KB LDS, manually overlaid across phases.
    __shared__ __align__(16) unsigned char smem[65536];
    __hip_bfloat16* s_h = (__hip_bfloat16*)(smem);           // [128][64]  P1-P2
    __hip_bfloat16* s_O = (__hip_bfloat16*)(smem + 16384);   // [128][64]  P2-P3
    __hip_bfloat16* s_x = (__hip_bfloat16*)(smem + 32768);   // [128][64]  P3-P4
    // P2 scratch (overlaps s_x region; dead before P3 writes s_x)
    __hip_bfloat16* s_wqT = (__hip_bfloat16*)(smem + 32768);           // [64][18]
    __hip_bfloat16* s_wkT = (__hip_bfloat16*)(smem + 32768 + 2304);    // [64][18]
    __hip_bfloat16* s_wvT = (__hip_bfloat16*)(smem + 32768 + 4608);    // [64][18]
    __hip_bfloat16* s_Q   = (__hip_bfloat16*)(smem + 32768 + 6912);    // [128][18]
    __hip_bfloat16* s_K   = (__hip_bfloat16*)(smem + 32768 + 11520);   // [128][18]
    __hip_bfloat16* s_V   = (__hip_bfloat16*)(smem + 32768 + 16128);   // [128][18] end 53504
    // P3 scratch (staged after last P2 barrier)
    __hip_bfloat16* s_woT = (__hip_bfloat16*)(smem + 49152);  // [64][66] end 57600
    // P4 scratch (s_h/s_O dead; s_woT dead)
    __hip_bfloat16* s_w2T = (__hip_bfloat16*)(smem);          // [128][66] end 16896
    __hip_bfloat16* s_w1T = (__hip_bfloat16*)(smem + 49152);  // [64][128] end 65536

    const int g    = blockIdx.x;
    const int b    = g >> 7;     // / TDIM
    const int t    = g & 127;
    const int tid  = threadIdx.x;
    const int lane = tid & 63;
    const int wave = tid >> 6;

    // ---------------- P1: stage h_flat[g] = h[b,:,t,:] ----------------
    const float* hp = h + (((size_t)b * DDIM) * TDIM + t) * HH;
    for (int idx = tid; idx < DDIM * HH; idx += NTHREADS) {
        int d = idx >> 6, j = idx & 63;
        s_h[idx] = f2bf(hp[(size_t)d * TDIM * HH + j]);
    }
    __syncthreads();

    // ---------------- P2: per-head QKV + attention ----------------
    const float* Wb = W + (size_t)b * DDIM * DDIM;
    for (int head = 0; head < NHEAD; ++head) {
        // stage transposed per-head weight columns (coalesced global reads)
        for (int idx = tid; idx < 1024; idx += NTHREADS) {
            int j = idx >> 6, k = idx & 63;
            int src = (HDIM * head + j) * HH + k;
            s_wqT[k * 18 + j] = f2bf(wq[src]);
            s_wkT[k * 18 + j] = f2bf(wk[src]);
            s_wvT[k * 18 + j] = f2bf(wv[src]);
        }
        __syncthreads();
        // QKV projection: thread -> (j in head, 4 rows d)
        {
            int j = tid & 15;
            int dbase = tid >> 4;  // 0..31
            float bqv = bq[HDIM * head + j];
            float bkv = bk[HDIM * head + j];
            float bvv = bv[HDIM * head + j];
            for (int dd = 0; dd < 4; ++dd) {
                int d = dbase + 32 * dd;
                float aq = 0.f, ak = 0.f, av = 0.f;
#pragma unroll 16
                for (int k = 0; k < 64; ++k) {
                    float hv = bf2f(s_h[d * 64 + k]);
                    aq += hv * bf2f(s_wqT[k * 18 + j]);
                    ak += hv * bf2f(s_wkT[k * 18 + j]);
                    av += hv * bf2f(s_wvT[k * 18 + j]);
                }
                s_Q[d * 18 + j] = f2bf((aq + bqv) * 0.25f);  // fold 1/sqrt(hd)
                s_K[d * 18 + j] = f2bf(ak + bkv);
                s_V[d * 18 + j] = f2bf(av + bvv);
            }
        }
        __syncthreads();
        // attention: one wave per q row; lane owns k=lane and k=lane+64
        {
            float weh = we[head], beh = be[head];
            int k1 = lane, k2 = lane + 64;
            for (int q = wave; q < DDIM; q += 8) {
                float qv[16];
#pragma unroll
                for (int j2 = 0; j2 < 16; ++j2) qv[j2] = bf2f(s_Q[q * 18 + j2]);
                float s1 = 0.f, s2 = 0.f;
#pragma unroll
                for (int j2 = 0; j2 < 16; ++j2) {
                    s1 += qv[j2] * bf2f(s_K[k1 * 18 + j2]);
                    s2 += qv[j2] * bf2f(s_K[k2 * 18 + j2]);
                }
                const float* Wrow = Wb + (size_t)q * DDIM;
                s1 += Wrow[k1] * weh + beh;
                s2 += Wrow[k2] * weh + beh;
                float mx = wredmax(fmaxf(s1, s2));
                float p1 = __expf(s1 - mx), p2 = __expf(s2 - mx);
                float sinv = 1.f / wredsum(p1 + p2);
                p1 *= sinv; p2 *= sinv;
                float keep = 0.f;
#pragma unroll
                for (int j2 = 0; j2 < 16; ++j2) {
                    float a = p1 * bf2f(s_V[k1 * 18 + j2]) + p2 * bf2f(s_V[k2 * 18 + j2]);
                    a = wredsum(a);
                    if (lane == j2) keep = a;   // keep static-indexed, no scratch
                }
                if (lane < 16) s_O[q * 64 + HDIM * head + lane] = f2bf(keep);
            }
        }
        __syncthreads();
    }

    // ---------------- P3: out-proj + residual (fp32 h from global) + LN1 ----------------
    for (int idx = tid; idx < HH * HH; idx += NTHREADS) {
        int j = idx >> 6, k = idx & 63;
        s_woT[k * 66 + j] = f2bf(wo[j * HH + k]);
    }
    __syncthreads();
    {
        float bov = bo[lane], g1v = g1[lane], b1v = b1[lane];
        for (int d = wave; d < DDIM; d += 8) {
            float acc = bov;
#pragma unroll 8
            for (int k = 0; k < 64; ++k)
                acc += bf2f(s_O[d * 64 + k]) * bf2f(s_woT[k * 66 + lane]);
            // residual in fp32 straight from global h (L3-resident, coalesced)
            float r = hp[(size_t)d * TDIM * HH + lane] + acc;
            float mu = wredsum(r) * (1.f / 64.f);
            float df = r - mu;
            float var = wredsum(df * df) * (1.f / 64.f);
            float xv = df * rsqrtf(var + 1e-5f) * g1v + b1v;
            s_x[d * 64 + lane] = f2bf(xv);
        }
    }
    __syncthreads();

    // ---------------- P4: FFN fused + residual + LN2 + store ----------------
    for (int idx = tid; idx < 8192; idx += NTHREADS) {   // w2T: coalesced global read
        int j = idx >> 7, m = idx & 127;                 // j 0..63, m 0..127
        s_w2T[m * 66 + j] = f2bf(w2[j * 128 + m]);
    }
    for (int idx = tid; idx < 8192; idx += NTHREADS) {   // w1T: coalesced global read
        int k = idx & 63, m = idx >> 6;                  // k 0..63, m 0..127
        s_w1T[k * 128 + m] = f2bf(w1[m * HH + k]);
    }
    __syncthreads();
    {
        float b10 = bf1[lane], b11 = bf1[lane + 64];
        float b2v = bff2[lane], g2v = g2[lane], b2b = b2[lane];
        float* outp = out + (((size_t)b * DDIM) * TDIM + t) * HH;
        for (int d = wave; d < DDIM; d += 8) {
            float a0 = b10, a1 = b11;
#pragma unroll 8
            for (int k = 0; k < 64; ++k) {
                float xv = bf2f(s_x[d * 64 + k]);
                a0 += xv * bf2f(s_w1T[k * 128 + lane]);
                a1 += xv * bf2f(s_w1T[k * 128 + lane + 64]);
            }
            a0 = 0.5f * a0 * (1.f + erff(a0 * 0.70710678118f));
            a1 = 0.5f * a1 * (1.f + erff(a1 * 0.70710678118f));
            // t1 row lives in the wave's registers: t1[m] = shfl(a0,m), t1[m+64] = shfl(a1,m)
            float f2a = b2v;
#pragma unroll 8
            for (int m = 0; m < 64; ++m) {
                float t0  = __shfl(a0, m);
                float t1v = __shfl(a1, m);
                f2a += t0  * bf2f(s_w2T[m * 66 + lane]);
                f2a += t1v * bf2f(s_w2T[(m + 64) * 66 + lane]);
            }
            float r2 = bf2f(s_x[d * 64 + lane]) + f2a;
            float mu = wredsum(r2) * (1.f / 64.f);
            float df = r2 - mu;
            float var = wredsum(df * df) * (1.f / 64.f);
            float yv = df * rsqrtf(var + 1e-5f) * g2v + b2b;
            outp[(size_t)d * TDIM * HH + lane] = yv;
        }
    }
}

extern "C" void kernel_launch(void* const* d_in, const int* in_sizes, int n_in,
                              void* d_out, int out_size, void* d_ws, size_t ws_size,
                              hipStream_t stream) {
    const float* h   = (const float*)d_in[0];
    const float* W   = (const float*)d_in[1];
    const float* wq  = (const float*)d_in[2];
    const float* bq  = (const float*)d_in[3];
    const float* wk  = (const float*)d_in[4];
    const float* bk  = (const float*)d_in[5];
    const float* wv  = (const float*)d_in[6];
    const float* bv  = (const float*)d_in[7];
    const float* wo  = (const float*)d_in[8];
    const float* bo  = (const float*)d_in[9];
    const float* we  = (const float*)d_in[10];
    const float* be  = (const float*)d_in[11];
    const float* g1  = (const float*)d_in[12];
    const float* b1  = (const float*)d_in[13];
    const float* w1  = (const float*)d_in[14];
    const float* bf1 = (const float*)d_in[15];
    const float* w2  = (const float*)d_in[16];
    const float* bf2 = (const float*)d_in[17];
    const float* g2  = (const float*)d_in[18];
    const float* b2  = (const float*)d_in[19];
    float* out = (float*)d_out;

    gal_kernel<<<NB * TDIM, NTHREADS, 0, stream>>>(
        h, W, wq, bq, wk, bk, wv, bv, wo, bo, we, be,
        g1, b1, w1, bf1, w2, bf2, g2, b2, out);
}

// Round 3
// 77.074 us; speedup vs baseline: 15.0726x; 15.0726x over previous
//
#include <hip/hip_runtime.h>
#include <hip/hip_bf16.h>

#define NTHREADS 512

typedef __attribute__((ext_vector_type(8))) short short8;
typedef __attribute__((ext_vector_type(4))) float f32x4;

#define MFMA(a, b, c) __builtin_amdgcn_mfma_f32_16x16x32_bf16(a, b, c, 0, 0, 0)

__device__ __forceinline__ unsigned short f2u(float x) {
    __hip_bfloat16 b = __float2bfloat16(x);
    return *reinterpret_cast<unsigned short*>(&b);
}
__device__ __forceinline__ float u2f(unsigned short u) {
    unsigned v = ((unsigned)u) << 16;
    return *reinterpret_cast<float*>(&v);
}
__device__ __forceinline__ unsigned pack2(float lo, float hi) {
    return ((unsigned)f2u(hi) << 16) | (unsigned)f2u(lo);
}
// XOR-swizzled byte offsets. [R][64] bf16 rows (128B, 8 chunks of 16B):
__device__ __forceinline__ int swz64(int r, int c8)  { return r * 128 + ((c8 ^ (r & 7)) << 4); }
__device__ __forceinline__ int swz64e(int r, int c)  { return r * 128 + (((c >> 3) ^ (r & 7)) << 4) + ((c & 7) << 1); }
// [R][128] bf16 rows (256B, 16 chunks):
__device__ __forceinline__ int swz128(int r, int c8) { return r * 256 + ((c8 ^ (r & 15)) << 4); }
__device__ __forceinline__ int swz128e(int r, int c) { return r * 256 + ((((c >> 3) ^ (r & 15))) << 4) + ((c & 7) << 1); }

__device__ __forceinline__ short8 cvt8(const float* src) {
    float4 f0 = *(const float4*)src;
    float4 f1 = *(const float4*)(src + 4);
    short8 v = { (short)f2u(f0.x), (short)f2u(f0.y), (short)f2u(f0.z), (short)f2u(f0.w),
                 (short)f2u(f1.x), (short)f2u(f1.y), (short)f2u(f1.z), (short)f2u(f1.w) };
    return v;
}

__global__ __launch_bounds__(NTHREADS, 4) void gal_kernel(
    const float* __restrict__ h,  const float* __restrict__ W,
    const float* __restrict__ wq, const float* __restrict__ bq,
    const float* __restrict__ wk, const float* __restrict__ bk,
    const float* __restrict__ wv, const float* __restrict__ bv,
    const float* __restrict__ wo, const float* __restrict__ bo,
    const float* __restrict__ we, const float* __restrict__ be,
    const float* __restrict__ g1, const float* __restrict__ b1,
    const float* __restrict__ w1, const float* __restrict__ bf1,
    const float* __restrict__ w2, const float* __restrict__ bff2,
    const float* __restrict__ g2, const float* __restrict__ b2,
    float* __restrict__ out)
{
    // 64 KB LDS, phase-overlaid:
    // A: s_h@0[128][64], wq@16K, wk@24K, wv@32K   (each [64][64])
    // B: s_Q@0[128][64], s_K@16K[128][64], s_VT@32K[64][128], s_O@48K[128][64]
    // C: s_wo@0[64][64], s_x@16K[128][64], s_O@48K live
    // D: s_x@16K, s_w1@32K[128][64], s_w2@48K[64][128]; then s_y fp32 @16K stride 68
    __shared__ __align__(16) unsigned char smem[65536];

    const int gblk = blockIdx.x;
    const int b   = gblk >> 7;
    const int tt  = gblk & 127;
    const int tid = threadIdx.x;
    const int lane = tid & 63;
    const int w   = tid >> 6;      // wave 0..7 = M/N-tile owner
    const int l15 = lane & 15;
    const int g   = lane >> 4;     // quarter-group 0..3

    const float* hp = h + (((size_t)b * 128) * 128 + tt) * 64;
    const float* Wb = W + (size_t)b * 128 * 128;

    // ================= Phase A: stage h + QKV weights =================
#pragma unroll
    for (int i = 0; i < 2; ++i) {
        int idx = tid + i * 512;
        int d = idx >> 3, c = idx & 7;
        *(short8*)(smem + swz64(d, c)) = cvt8(hp + (size_t)d * 8192 + c * 8);
    }
    {
        int j = tid >> 3, c = tid & 7;   // 512 threads cover 64x8 exactly
        *(short8*)(smem + 16384 + swz64(j, c)) = cvt8(wq + j * 64 + c * 8);
        *(short8*)(smem + 24576 + swz64(j, c)) = cvt8(wk + j * 64 + c * 8);
        *(short8*)(smem + 32768 + swz64(j, c)) = cvt8(wv + j * 64 + c * 8);
    }
    __syncthreads();

    // QKV GEMMs into registers: wave w owns rows 16w..16w+15
    f32x4 aq[4], ak4[4], av4[4];
    {
        short8 ah0 = *(const short8*)(smem + swz64(16 * w + l15, g));
        short8 ah1 = *(const short8*)(smem + swz64(16 * w + l15, g + 4));
        f32x4 z = {0.f, 0.f, 0.f, 0.f};
#pragma unroll
        for (int nt = 0; nt < 4; ++nt) { aq[nt] = z; ak4[nt] = z; av4[nt] = z; }
#pragma unroll
        for (int nt = 0; nt < 4; ++nt) {
#pragma unroll
            for (int kh = 0; kh < 2; ++kh) {
                short8 ah = kh ? ah1 : ah0;
                short8 bwq = *(const short8*)(smem + 16384 + swz64(16 * nt + l15, g + 4 * kh));
                aq[nt] = MFMA(ah, bwq, aq[nt]);
                short8 bwk = *(const short8*)(smem + 24576 + swz64(16 * nt + l15, g + 4 * kh));
                ak4[nt] = MFMA(ah, bwk, ak4[nt]);
                short8 bwv = *(const short8*)(smem + 32768 + swz64(16 * nt + l15, g + 4 * kh));
                av4[nt] = MFMA(ah, bwv, av4[nt]);
            }
        }
    }
    float bqv[4], bkv[4], bvv[4];
#pragma unroll
    for (int nt = 0; nt < 4; ++nt) {
        bqv[nt] = bq[16 * nt + l15]; bkv[nt] = bk[16 * nt + l15]; bvv[nt] = bv[16 * nt + l15];
    }
    __syncthreads();
    // write s_Q@0, s_K@16K (row d), s_VT@32K (row v=col j)
#pragma unroll
    for (int nt = 0; nt < 4; ++nt) {
        int j = 16 * nt + l15;
#pragma unroll
        for (int jr = 0; jr < 4; ++jr) {
            int d = 16 * w + 4 * g + jr;
            *(unsigned short*)(smem + swz64e(d, j))          = f2u((aq[nt][jr] + bqv[nt]) * 0.25f);
            *(unsigned short*)(smem + 16384 + swz64e(d, j))  = f2u(ak4[nt][jr] + bkv[nt]);
            *(unsigned short*)(smem + 32768 + swz128e(j, d)) = f2u(av4[nt][jr] + bvv[nt]);
        }
    }
    __syncthreads();

    // ================= Phase B: attention (swapped S^T = K*Q^T) =================
    const int q = 16 * w + l15;            // this lane's q-row (wave's q-tile)
    const int src0 = l15 + ((lane & 16) << 1);  // quarter-shuffle sources
    const int src1 = src0 + 16;
    const bool hiMt = (g >> 1) & 1;

    for (int hd = 0; hd < 4; ++hd) {
        float weh = we[hd], beh = be[hd];
        short8 qf = {0, 0, 0, 0, 0, 0, 0, 0};
        if (g < 2) qf = *(const short8*)(smem + swz64(q, 2 * hd + g));
        f32x4 s[8];
#pragma unroll
        for (int Mt = 0; Mt < 8; ++Mt) {
            float4 w4 = *(const float4*)(Wb + (size_t)q * 128 + 16 * Mt + 4 * g);
            f32x4 c0 = { w4.x * weh + beh, w4.y * weh + beh, w4.z * weh + beh, w4.w * weh + beh };
            short8 kf = {0, 0, 0, 0, 0, 0, 0, 0};
            if (g < 2) kf = *(const short8*)(smem + 16384 + swz64(16 * Mt + l15, 2 * hd + g));
            s[Mt] = MFMA(kf, qf, c0);
        }
        // softmax over kk (row q lives in 4 lanes x 32 regs)
        float mx = s[0][0];
#pragma unroll
        for (int Mt = 0; Mt < 8; ++Mt)
#pragma unroll
            for (int jr = 0; jr < 4; ++jr) mx = fmaxf(mx, s[Mt][jr]);
        mx = fmaxf(mx, __shfl_xor(mx, 16));
        mx = fmaxf(mx, __shfl_xor(mx, 32));
        float tot = 0.f;
#pragma unroll
        for (int Mt = 0; Mt < 8; ++Mt)
#pragma unroll
            for (int jr = 0; jr < 4; ++jr) { s[Mt][jr] = __expf(s[Mt][jr] - mx); tot += s[Mt][jr]; }
        tot += __shfl_xor(tot, 16);
        tot += __shfl_xor(tot, 32);
        float sinv = 1.f / tot;
        // pack P to bf16 pairs: pk[2Mt]=(jr0,jr1), pk[2Mt+1]=(jr2,jr3)
        unsigned pk[16];
#pragma unroll
        for (int Mt = 0; Mt < 8; ++Mt) {
            pk[2 * Mt]     = pack2(s[Mt][0], s[Mt][1]);
            pk[2 * Mt + 1] = pack2(s[Mt][2], s[Mt][3]);
        }
        // PV: out^T = V^T @ P^T
        f32x4 o = {0.f, 0.f, 0.f, 0.f};
#pragma unroll
        for (int kc = 0; kc < 4; ++kc) {
            unsigned a0 = __shfl((int)pk[4 * kc + 0], src0), a1 = __shfl((int)pk[4 * kc + 1], src0);
            unsigned b0 = __shfl((int)pk[4 * kc + 2], src0), b1 = __shfl((int)pk[4 * kc + 3], src0);
            unsigned a2 = __shfl((int)pk[4 * kc + 0], src1), a3 = __shfl((int)pk[4 * kc + 1], src1);
            unsigned b2 = __shfl((int)pk[4 * kc + 2], src1), b3 = __shfl((int)pk[4 * kc + 3], src1);
            union { unsigned u[4]; short8 s8; } pf;
            pf.u[0] = hiMt ? b0 : a0;
            pf.u[1] = hiMt ? b1 : a1;
            pf.u[2] = hiMt ? b2 : a2;
            pf.u[3] = hiMt ? b3 : a3;
            short8 vf = *(const short8*)(smem + 32768 + swz128(16 * hd + l15, g + 4 * kc));
            o = MFMA(vf, pf.s8, o);
        }
#pragma unroll
        for (int jr = 0; jr < 4; ++jr)
            *(unsigned short*)(smem + 49152 + swz64e(q, 16 * hd + 4 * g + jr)) = f2u(o[jr] * sinv);
    }
    __syncthreads();

    // ================= Phase C: out-proj + residual + LN1 =================
    {
        int j = tid >> 3, c = tid & 7;
        *(short8*)(smem + swz64(j, c)) = cvt8(wo + j * 64 + c * 8);
    }
    __syncthreads();
    {
        short8 ao0 = *(const short8*)(smem + 49152 + swz64(16 * w + l15, g));
        short8 ao1 = *(const short8*)(smem + 49152 + swz64(16 * w + l15, g + 4));
        f32x4 xo[4];
        float g1v[4], b1v[4];
#pragma unroll
        for (int nt = 0; nt < 4; ++nt) {
            float bov = bo[16 * nt + l15];
            f32x4 c0 = { bov, bov, bov, bov };
            xo[nt] = c0;
            g1v[nt] = g1[16 * nt + l15];
            b1v[nt] = b1[16 * nt + l15];
        }
#pragma unroll
        for (int nt = 0; nt < 4; ++nt)
#pragma unroll
            for (int kh = 0; kh < 2; ++kh) {
                short8 bw = *(const short8*)(smem + swz64(16 * nt + l15, g + 4 * kh));
                xo[nt] = MFMA(kh ? ao1 : ao0, bw, xo[nt]);
            }
        float r[4][4];
#pragma unroll
        for (int nt = 0; nt < 4; ++nt)
#pragma unroll
            for (int jr = 0; jr < 4; ++jr)
                r[nt][jr] = xo[nt][jr] + hp[(size_t)(16 * w + 4 * g + jr) * 8192 + 16 * nt + l15];
#pragma unroll
        for (int jr = 0; jr < 4; ++jr) {
            float ps = 0.f, pq = 0.f;
#pragma unroll
            for (int nt = 0; nt < 4; ++nt) { ps += r[nt][jr]; pq += r[nt][jr] * r[nt][jr]; }
#pragma unroll
            for (int off = 1; off <= 8; off <<= 1) { ps += __shfl_xor(ps, off); pq += __shfl_xor(pq, off); }
            float mu = ps * (1.f / 64.f);
            float va = pq * (1.f / 64.f) - mu * mu;
            float is = rsqrtf(va + 1e-5f);
            int d = 16 * w + 4 * g + jr;
#pragma unroll
            for (int nt = 0; nt < 4; ++nt) {
                float xv = (r[nt][jr] - mu) * is * g1v[nt] + b1v[nt];
                *(unsigned short*)(smem + 16384 + swz64e(d, 16 * nt + l15)) = f2u(xv);
            }
        }
    }
    __syncthreads();

    // ================= Phase D: FFN (transposed) + residual + LN2 =================
#pragma unroll
    for (int i = 0; i < 2; ++i) {      // s_w1@32K [128][64]
        int idx = tid + i * 512;
        int m = idx >> 3, c = idx & 7;
        *(short8*)(smem + 32768 + swz64(m, c)) = cvt8(w1 + m * 64 + c * 8);
    }
#pragma unroll
    for (int i = 0; i < 2; ++i) {      // s_w2@48K [64][128]
        int idx = tid + i * 512;
        int j = idx >> 4, c = idx & 15;
        *(short8*)(smem + 49152 + swz128(j, c)) = cvt8(w2 + j * 128 + c * 8);
    }
    __syncthreads();

    float rr[4][4];
    {
        short8 bx0 = *(const short8*)(smem + 16384 + swz64(16 * w + l15, g));
        short8 bx1 = *(const short8*)(smem + 16384 + swz64(16 * w + l15, g + 4));
        // FFN1: t^T = w1 @ x^T  (C: row m=4g+jr+16Mt, col q=l15)
        f32x4 tacc[8];
        f32x4 z = {0.f, 0.f, 0.f, 0.f};
#pragma unroll
        for (int Mt = 0; Mt < 8; ++Mt) tacc[Mt] = z;
#pragma unroll
        for (int Mt = 0; Mt < 8; ++Mt)
#pragma unroll
            for (int kh = 0; kh < 2; ++kh) {
                short8 aw1 = *(const short8*)(smem + 32768 + swz64(16 * Mt + l15, g + 4 * kh));
                tacc[Mt] = MFMA(aw1, kh ? bx1 : bx0, tacc[Mt]);
            }
        unsigned pkt[16];
#pragma unroll
        for (int Mt = 0; Mt < 8; ++Mt) {
            float4 bb = *(const float4*)(bf1 + 16 * Mt + 4 * g);
            float v0 = tacc[Mt][0] + bb.x, v1 = tacc[Mt][1] + bb.y;
            float v2 = tacc[Mt][2] + bb.z, v3 = tacc[Mt][3] + bb.w;
            v0 = 0.5f * v0 * (1.f + erff(v0 * 0.70710678118f));
            v1 = 0.5f * v1 * (1.f + erff(v1 * 0.70710678118f));
            v2 = 0.5f * v2 * (1.f + erff(v2 * 0.70710678118f));
            v3 = 0.5f * v3 * (1.f + erff(v3 * 0.70710678118f));
            pkt[2 * Mt]     = pack2(v0, v1);
            pkt[2 * Mt + 1] = pack2(v2, v3);
        }
        // FFN2: y^T = w2 @ t^T
        f32x4 ya[4];
#pragma unroll
        for (int Mt2 = 0; Mt2 < 4; ++Mt2) {
            float4 bb = *(const float4*)(bff2 + 16 * Mt2 + 4 * g);
            f32x4 c0 = { bb.x, bb.y, bb.z, bb.w };
            ya[Mt2] = c0;
        }
#pragma unroll
        for (int kc = 0; kc < 4; ++kc) {
            unsigned a0 = __shfl((int)pkt[4 * kc + 0], src0), a1 = __shfl((int)pkt[4 * kc + 1], src0);
            unsigned b0 = __shfl((int)pkt[4 * kc + 2], src0), b1 = __shfl((int)pkt[4 * kc + 3], src0);
            unsigned a2 = __shfl((int)pkt[4 * kc + 0], src1), a3 = __shfl((int)pkt[4 * kc + 1], src1);
            unsigned b2 = __shfl((int)pkt[4 * kc + 2], src1), b3 = __shfl((int)pkt[4 * kc + 3], src1);
            union { unsigned u[4]; short8 s8; } pf;
            pf.u[0] = hiMt ? b0 : a0;
            pf.u[1] = hiMt ? b1 : a1;
            pf.u[2] = hiMt ? b2 : a2;
            pf.u[3] = hiMt ? b3 : a3;
#pragma unroll
            for (int Mt2 = 0; Mt2 < 4; ++Mt2) {
                short8 aw2 = *(const short8*)(smem + 49152 + swz128(16 * Mt2 + l15, g + 4 * kc));
                ya[Mt2] = MFMA(aw2, pf.s8, ya[Mt2]);
            }
        }
        // residual (x from LDS bf16) + LN2, all in regs
        float ps = 0.f, pq = 0.f;
#pragma unroll
        for (int Mt2 = 0; Mt2 < 4; ++Mt2)
#pragma unroll
            for (int jr = 0; jr < 4; ++jr) {
                unsigned short xu = *(const unsigned short*)(smem + 16384 + swz64e(q, 16 * Mt2 + 4 * g + jr));
                float v = ya[Mt2][jr] + u2f(xu);
                rr[Mt2][jr] = v;
                ps += v; pq += v * v;
            }
        ps += __shfl_xor(ps, 16); ps += __shfl_xor(ps, 32);
        pq += __shfl_xor(pq, 16); pq += __shfl_xor(pq, 32);
        float mu = ps * (1.f / 64.f);
        float va = pq * (1.f / 64.f) - mu * mu;
        float is = rsqrtf(va + 1e-5f);
#pragma unroll
        for (int Mt2 = 0; Mt2 < 4; ++Mt2) {
            float4 g4 = *(const float4*)(g2 + 16 * Mt2 + 4 * g);
            float4 b4 = *(const float4*)(b2 + 16 * Mt2 + 4 * g);
            rr[Mt2][0] = (rr[Mt2][0] - mu) * is * g4.x + b4.x;
            rr[Mt2][1] = (rr[Mt2][1] - mu) * is * g4.y + b4.y;
            rr[Mt2][2] = (rr[Mt2][2] - mu) * is * g4.z + b4.z;
            rr[Mt2][3] = (rr[Mt2][3] - mu) * is * g4.w + b4.w;
        }
    }
    __syncthreads();                   // all x/w1/w2 reads done
    {
        float* sy = (float*)(smem + 16384);   // [128][68] fp32
#pragma unroll
        for (int Mt2 = 0; Mt2 < 4; ++Mt2)
#pragma unroll
            for (int jr = 0; jr < 4; ++jr)
                sy[q * 68 + 16 * Mt2 + 4 * g + jr] = rr[Mt2][jr];
    }
    __syncthreads();
    {
        int qq = tid >> 2, jb = (tid & 3) * 16;
        const float* sp = (const float*)(smem + 16384) + qq * 68 + jb;
        float* op = out + (((size_t)b * 128) * 128 + tt) * 64 + (size_t)qq * 8192 + jb;
        float4 v0 = *(const float4*)(sp);
        float4 v1 = *(const float4*)(sp + 4);
        float4 v2 = *(const float4*)(sp + 8);
        float4 v3 = *(const float4*)(sp + 12);
        *(float4*)(op)      = v0;
        *(float4*)(op + 4)  = v1;
        *(float4*)(op + 8)  = v2;
        *(float4*)(op + 12) = v3;
    }
}

extern "C" void kernel_launch(void* const* d_in, const int* in_sizes, int n_in,
                              void* d_out, int out_size, void* d_ws, size_t ws_size,
                              hipStream_t stream) {
    const float* h   = (const float*)d_in[0];
    const float* W   = (const float*)d_in[1];
    const float* wq  = (const float*)d_in[2];
    const float* bq  = (const float*)d_in[3];
    const float* wk  = (const float*)d_in[4];
    const float* bk  = (const float*)d_in[5];
    const float* wv  = (const float*)d_in[6];
    const float* bv  = (const float*)d_in[7];
    const float* wo  = (const float*)d_in[8];
    const float* bo  = (const float*)d_in[9];
    const float* we  = (const float*)d_in[10];
    const float* be  = (const float*)d_in[11];
    const float* g1  = (const float*)d_in[12];
    const float* b1  = (const float*)d_in[13];
    const float* w1  = (const float*)d_in[14];
    const float* bf1 = (const float*)d_in[15];
    const float* w2  = (const float*)d_in[16];
    const float* bf2 = (const float*)d_in[17];
    const float* g2  = (const float*)d_in[18];
    const float* b2  = (const float*)d_in[19];
    float* out = (float*)d_out;

    gal_kernel<<<1024, NTHREADS, 0, stream>>>(
        h, W, wq, bq, wk, bk, wv, bv, wo, bo, we, be,
        g1, b1, w1, bf1, w2, bf2, g2, b2, out);
}